// Round 2
// baseline (751.606 us; speedup 1.0000x reference)
//
#include <hip/hip_runtime.h>
#include <hip/hip_bf16.h>

#define NN 50000
#define NE 1600000
#define FF 128
#define CC 16

using bf16 = __hip_bfloat16;

// Runtime-dtype load: isbf selects bf16 vs f32 interpretation of p.
static __device__ __forceinline__ float ldf(const void* p, int i, int isbf){
    return isbf ? __bfloat162float(((const bf16*)p)[i]) : ((const float*)p)[i];
}

// ---------------- dtype detector ----------------
// Sample low 16 bits of the first 256 dwords of feat. If the buffer is bf16,
// those are genuine bf16 values ~N(0,1): exponent field in [117,137] ~99.9%.
// If f32, they are low mantissa bits: exponent field uniform -> ~8% "sane".
__global__ __launch_bounds__(256) void k_detect(const unsigned short* __restrict__ u,
                                                int* __restrict__ flag){
    int t = threadIdx.x;
    unsigned short lo = u[2 * t];
    int e = (lo >> 7) & 0xFF;
    int sane = (e >= 117 && e <= 137) ? 1 : 0;
    __shared__ int cnt;
    if (t == 0) cnt = 0;
    __syncthreads();
    atomicAdd(&cnt, sane);
    __syncthreads();
    if (t == 0) *flag = (cnt >= 128) ? 1 : 0;   // 1 => bf16 data
}

__global__ __launch_bounds__(256) void k_zero(int* __restrict__ p, int n){
    int i = blockIdx.x * 256 + threadIdx.x;
    if (i < n) p[i] = 0;
}

// ---------------- CSR build ----------------

__global__ __launch_bounds__(256) void k_degree(const int* __restrict__ dst, int* __restrict__ deg){
    int i = blockIdx.x * 256 + threadIdx.x;
    if (i < NE){
        int d = dst[i];
        if ((unsigned)d >= NN) d = 0;   // defensive clamp
        atomicAdd(&deg[d], 1);
    }
}

__global__ __launch_bounds__(256) void k_scan1(const int* __restrict__ deg, int* __restrict__ blksums){
    __shared__ int s[256];
    int t = threadIdx.x;
    int i = blockIdx.x * 256 + t;
    int v = (i < NN) ? deg[i] : 0;
    s[t] = v; __syncthreads();
    for (int off = 128; off; off >>= 1){ if (t < off) s[t] += s[t + off]; __syncthreads(); }
    if (t == 0) blksums[blockIdx.x] = s[0];
}

__global__ __launch_bounds__(256) void k_scan2(const int* __restrict__ blksums, int* __restrict__ blkoff,
                                               int* __restrict__ rowptr, int nblk){
    __shared__ int s[256];
    int t = threadIdx.x;
    int v = (t < nblk) ? blksums[t] : 0;
    s[t] = v; __syncthreads();
    for (int off = 1; off < 256; off <<= 1){
        int x = (t >= off) ? s[t - off] : 0;
        __syncthreads();
        s[t] += x;
        __syncthreads();
    }
    blkoff[t] = s[t] - v;                 // exclusive
    if (t == 255) rowptr[NN] = s[255];    // total == NE
}

__global__ __launch_bounds__(256) void k_scan3(const int* __restrict__ deg, const int* __restrict__ blkoff,
                                               int* __restrict__ rowptr, int* __restrict__ cursor){
    __shared__ int s[256];
    int t = threadIdx.x;
    int i = blockIdx.x * 256 + t;
    int v = (i < NN) ? deg[i] : 0;
    s[t] = v; __syncthreads();
    for (int off = 1; off < 256; off <<= 1){
        int x = (t >= off) ? s[t - off] : 0;
        __syncthreads();
        s[t] += x;
        __syncthreads();
    }
    if (i < NN){
        int val = blkoff[blockIdx.x] + s[t] - v;  // exclusive prefix
        rowptr[i] = val;
        cursor[i] = val;
    }
}

__global__ __launch_bounds__(256) void k_scatter(const int* __restrict__ src, const int* __restrict__ dst,
                                                 int* __restrict__ cursor, int* __restrict__ csrsrc){
    int i = blockIdx.x * 256 + threadIdx.x;
    if (i < NE){
        int d = dst[i];
        if ((unsigned)d >= NN) d = 0;
        int p = atomicAdd(&cursor[d], 1);
        if ((unsigned)p < NE) csrsrc[p] = src[i];
    }
}

// ---------------- GEMM: ft = X @ W  (X: [NN,FF], W: [FF,OUT] row-major) ----------------
// Block = 256 threads, tile = BN=16 nodes. X tile staged transposed in LDS (padded).
// XDYN: X dtype follows runtime flag (layer 1); else X is f32 workspace.

template<bool XDYN, int OUT, int NPT>
__global__ __launch_bounds__(256) void k_gemm(const void* __restrict__ X, const void* __restrict__ W,
                                              const int* __restrict__ dflag, float* __restrict__ ft){
    constexpr int BN = 256 * NPT / OUT;   // 16 for both instantiations
    __shared__ float xs[FF][BN + 1];      // transposed, +1 pad kills store conflicts
    const int isbf = *dflag;
    const int t  = threadIdx.x;
    const int n0 = blockIdx.x * BN;

    for (int idx = t; idx < BN * FF; idx += 256){
        int r = idx >> 7;        // node within tile
        int c = idx & 127;       // feature
        int n = n0 + r;
        float v = 0.f;
        if (n < NN){
            if (XDYN) v = ldf(X, n * FF + c, isbf);
            else      v = ((const float*)X)[n * FF + c];
        }
        xs[c][r] = v;
    }
    __syncthreads();

    const int tx = t % OUT;
    const int rg = t / OUT;      // row group
    float acc[NPT];
    #pragma unroll
    for (int i = 0; i < NPT; i++) acc[i] = 0.f;

    if (isbf){
        const bf16* Wb = (const bf16*)W;
        for (int k = 0; k < FF; k++){
            float w = __bfloat162float(Wb[k * OUT + tx]);
            #pragma unroll
            for (int i = 0; i < NPT; i++) acc[i] += w * xs[k][rg * NPT + i];
        }
    } else {
        const float* Wf = (const float*)W;
        for (int k = 0; k < FF; k++){
            float w = Wf[k * OUT + tx];
            #pragma unroll
            for (int i = 0; i < NPT; i++) acc[i] += w * xs[k][rg * NPT + i];
        }
    }

    #pragma unroll
    for (int i = 0; i < NPT; i++){
        int n = n0 + rg * NPT + i;
        if (n < NN) ft[n * OUT + tx] = acc[i];
    }
}

// ---------------- el/er: per-node dot with attention vectors ----------------

template<int OUT>
__global__ __launch_bounds__(256) void k_el_er(const float* __restrict__ ft, const void* __restrict__ al,
                                               const void* __restrict__ ar, const int* __restrict__ dflag,
                                               float* __restrict__ el, float* __restrict__ er){
    const int isbf = *dflag;
    int lane = threadIdx.x & 63;
    int n = blockIdx.x * 4 + (threadIdx.x >> 6);
    if (n >= NN) return;
    float pl = 0.f, pr = 0.f;
    if (OUT == 128){
        float v0 = ft[n * 128 + lane];
        float v1 = ft[n * 128 + 64 + lane];
        pl = v0 * ldf(al, lane, isbf) + v1 * ldf(al, 64 + lane, isbf);
        pr = v0 * ldf(ar, lane, isbf) + v1 * ldf(ar, 64 + lane, isbf);
    } else {
        if (lane < OUT){
            float v = ft[n * OUT + lane];
            pl = v * ldf(al, lane, isbf);
            pr = v * ldf(ar, lane, isbf);
        }
    }
    #pragma unroll
    for (int off = 32; off; off >>= 1){
        pl += __shfl_xor(pl, off);
        pr += __shfl_xor(pr, off);
    }
    if (lane == 0){ el[n] = pl; er[n] = pr; }
}

// ---------------- Aggregation: one wave per dst node, edge softmax + weighted sum ----------------
// FINAL: write output in runtime dtype (flag). Otherwise f32 workspace.

template<int OUT, bool FINAL>
__global__ __launch_bounds__(256) void k_agg(const float* __restrict__ ft, const float* __restrict__ el,
                                             const float* __restrict__ er, const int* __restrict__ rowptr,
                                             const int* __restrict__ csrsrc, const void* __restrict__ bias,
                                             const int* __restrict__ dflag, void* __restrict__ outp){
    const int isbf = *dflag;
    int lane = threadIdx.x & 63;
    int n = blockIdx.x * 4 + (threadIdx.x >> 6);
    if (n >= NN) return;
    int beg = rowptr[n], end = rowptr[n + 1];
    beg = (beg < 0) ? 0 : (beg > NE ? NE : beg);        // defensive clamps
    end = (end < beg) ? beg : (end > NE ? NE : end);
    int deg = end - beg;
    float erd = er[n];

    // Pass 1: parallel max over incoming edges; cache first 64 (src, logit) in registers.
    float m = -3.4e38f;
    int   s_c = 0;
    float e_c = 0.f;
    for (int i = beg + lane; i < end; i += 64){
        int s = csrsrc[i];
        if ((unsigned)s >= NN) s = 0;
        float e = el[s] + erd;
        e = (e >= 0.f) ? e : 0.2f * e;       // LeakyReLU, slope 0.2
        if (i < beg + 64){ s_c = s; e_c = e; }
        m = fmaxf(m, e);
    }
    #pragma unroll
    for (int off = 32; off; off >>= 1) m = fmaxf(m, __shfl_xor(m, off));

    // Pass 2: sequential over edges (wave-uniform), parallel over features.
    float acc0 = 0.f, acc1 = 0.f, lsum = 0.f;
    int jmax = (deg < 64) ? deg : 64;
    int fidx = (OUT == 128) ? lane : (lane & (OUT - 1));
    for (int j = 0; j < jmax; ++j){
        int   s = __shfl(s_c, j);
        float w = __expf(__shfl(e_c, j) - m);
        lsum += w;
        acc0 += w * ft[s * OUT + fidx];
        if constexpr (OUT == 128) acc1 += w * ft[s * 128 + 64 + lane];
    }
    // Rare tail (deg > 64): direct loads, wave-uniform i.
    for (int i = beg + 64; i < end; ++i){
        int s = csrsrc[i];
        if ((unsigned)s >= NN) s = 0;
        float e = el[s] + erd;
        e = (e >= 0.f) ? e : 0.2f * e;
        float w = __expf(e - m);
        lsum += w;
        acc0 += w * ft[s * OUT + fidx];
        if constexpr (OUT == 128) acc1 += w * ft[s * 128 + 64 + lane];
    }

    float inv = 1.f / ((lsum > 0.f) ? lsum : 1.f);
    if constexpr (OUT == 128){
        float o0 = fmaxf(acc0 * inv + ldf(bias, lane, isbf), 0.f);
        float o1 = fmaxf(acc1 * inv + ldf(bias, 64 + lane, isbf), 0.f);
        float* out = (float*)outp;
        out[n * 128 + lane] = o0;
        out[n * 128 + 64 + lane] = o1;
    } else {
        if (lane < OUT){
            float o = fmaxf(acc0 * inv + ldf(bias, lane, isbf), 0.f);
            if (FINAL && isbf) ((bf16*)outp)[n * OUT + lane] = __float2bfloat16(o);
            else               ((float*)outp)[n * OUT + lane] = o;
        }
    }
}

// ---------------- host launch ----------------

static size_t align256(size_t x){ return (x + 255) & ~(size_t)255; }

extern "C" void kernel_launch(void* const* d_in, const int* in_sizes, int n_in,
                              void* d_out, int out_size, void* d_ws, size_t ws_size,
                              hipStream_t stream) {
    const void* feat = d_in[0];
    const int*  src  = (const int*)d_in[1];
    const int*  dst  = (const int*)d_in[2];
    const void* W1 = d_in[3];
    const void* al1= d_in[4];
    const void* ar1= d_in[5];
    const void* b1 = d_in[6];
    const void* W2 = d_in[7];
    const void* al2= d_in[8];
    const void* ar2= d_in[9];
    const void* b2 = d_in[10];
    const void* W3 = d_in[11];
    const void* al3= d_in[12];
    const void* ar3= d_in[13];
    const void* b3 = d_in[14];

    // workspace carve
    char* p = (char*)d_ws;
    size_t off = 0;
    auto carve = [&](size_t bytes)->void*{
        void* r = p + off;
        off += align256(bytes);
        return r;
    };
    float* ftA   = (float*)carve((size_t)NN * FF * 4);   // transformed features; reused as ft3 in layer 3
    float* hB    = (float*)carve((size_t)NN * FF * 4);   // hidden state
    float* el    = (float*)carve((size_t)NN * 4);
    float* er    = (float*)carve((size_t)NN * 4);
    int*   deg   = (int*)  carve((size_t)NN * 4);
    int*   rowptr= (int*)  carve((size_t)(NN + 1) * 4);
    int*   cursor= (int*)  carve((size_t)NN * 4);
    int*   csrsrc= (int*)  carve((size_t)NE * 4);
    int*   blksums=(int*)  carve(256 * 4);
    int*   blkoff =(int*)  carve(256 * 4);
    int*   dflag  =(int*)  carve(256);
    float* ft3   = ftA;   // layer-3 transformed features [NN,16] overlay
    (void)ws_size; (void)n_in; (void)in_sizes; (void)out_size;

    const int nblk_scan = (NN + 255) / 256;   // 196
    dim3 b256(256);

    // dtype detection (inputs are either all-f32 or all-bf16)
    k_detect<<<dim3(1), b256, 0, stream>>>((const unsigned short*)feat, dflag);

    // CSR build (every call: ws is re-poisoned by the harness)
    k_zero<<<dim3(nblk_scan), b256, 0, stream>>>(deg, NN);
    k_degree<<<dim3((NE + 255) / 256), b256, 0, stream>>>(dst, deg);
    k_scan1<<<dim3(nblk_scan), b256, 0, stream>>>(deg, blksums);
    k_scan2<<<dim3(1), b256, 0, stream>>>(blksums, blkoff, rowptr, nblk_scan);
    k_scan3<<<dim3(nblk_scan), b256, 0, stream>>>(deg, blkoff, rowptr, cursor);
    k_scatter<<<dim3((NE + 255) / 256), b256, 0, stream>>>(src, dst, cursor, csrsrc);

    const int gemm_grid = (NN + 15) / 16;     // 3125
    const int node_grid = (NN + 3) / 4;       // 12500

    // Layer 1: feat @ W1 -> ftA; agg -> hB
    k_gemm<true, 128, 8><<<dim3(gemm_grid), b256, 0, stream>>>(feat, W1, dflag, ftA);
    k_el_er<128><<<dim3(node_grid), b256, 0, stream>>>(ftA, al1, ar1, dflag, el, er);
    k_agg<128, false><<<dim3(node_grid), b256, 0, stream>>>(ftA, el, er, rowptr, csrsrc, b1, dflag, hB);

    // Layer 2: hB @ W2 -> ftA; agg -> hB (GEMM finishes reading hB before agg rewrites it)
    k_gemm<false, 128, 8><<<dim3(gemm_grid), b256, 0, stream>>>(hB, W2, dflag, ftA);
    k_el_er<128><<<dim3(node_grid), b256, 0, stream>>>(ftA, al2, ar2, dflag, el, er);
    k_agg<128, false><<<dim3(node_grid), b256, 0, stream>>>(ftA, el, er, rowptr, csrsrc, b2, dflag, hB);

    // Layer 3: hB @ W3 -> ft3; agg -> d_out (dtype per flag)
    k_gemm<false, 16, 1><<<dim3(gemm_grid), b256, 0, stream>>>(hB, W3, dflag, ft3);
    k_el_er<16><<<dim3(node_grid), b256, 0, stream>>>(ft3, al3, ar3, dflag, el, er);
    k_agg<16, true><<<dim3(node_grid), b256, 0, stream>>>(ft3, el, er, rowptr, csrsrc, b3, dflag, d_out);
}